// Round 2
// baseline (529.528 us; speedup 1.0000x reference)
//
#include <hip/hip_runtime.h>

typedef __attribute__((ext_vector_type(8))) short bf16x8;
typedef __attribute__((ext_vector_type(4))) float f32x4;
typedef unsigned short ushort_t;

// ---------------------------------------------------------------------------
// fp32 -> bf16 RNE, and hi/lo split helpers
// ---------------------------------------------------------------------------
__device__ inline unsigned f2bf_bits(float f) {
    unsigned u = __float_as_uint(f);
    return (u + 0x7FFFu + ((u >> 16) & 1u)) >> 16;
}

__device__ inline void split8(const float4 a, const float4 b, bf16x8& hv, bf16x8& lv) {
    float f[8] = {a.x, a.y, a.z, a.w, b.x, b.y, b.z, b.w};
#pragma unroll
    for (int j = 0; j < 8; ++j) {
        unsigned hb = f2bf_bits(f[j]);
        float hf = __uint_as_float(hb << 16);
        unsigned lb = f2bf_bits(f[j] - hf);
        hv[j] = (short)hb;
        lv[j] = (short)lb;
    }
}

// ---------------------------------------------------------------------------
// Kernel 1: pack W_in [64][1024] fp32 -> Wp bf16 hi/lo, MFMA-fragment layout.
// Wp linear ushort index o = g*16384 + chsub*4096 + hl*2048 + kg*512 + n*8 + j
//   where k = g*128 + chsub*32 + kg*8 + j   (g = 128-wide K group staged per iter)
// ---------------------------------------------------------------------------
__global__ void pack_w_kernel(const float* __restrict__ Win, ushort_t* __restrict__ Wp) {
    int o = blockIdx.x * 256 + threadIdx.x;   // 0..131071
    int j     = o & 7;
    int n     = (o >> 3) & 63;
    int kg    = (o >> 9) & 3;
    int hl    = (o >> 11) & 1;
    int chsub = (o >> 12) & 3;
    int g     = o >> 14;
    int k = g * 128 + chsub * 32 + kg * 8 + j;
    float v = Win[n * 1024 + k];
    unsigned hb = f2bf_bits(v);
    unsigned lb = f2bf_bits(v - __uint_as_float(hb << 16));
    Wp[o] = (ushort_t)(hl ? lb : hb);
}

// ---------------------------------------------------------------------------
// Kernel 2: ext = x @ W_in^T + b_in  via bf16 MFMA, 3-term hi/lo split.
// M=131072, N=64, K=1024.  BM=64 (4 waves x 16 rows), BN=64, BK=128.
// A: per-lane global->reg (512B contiguous per row per iter -> DRAM-friendly),
//    converted to bf16 hi/lo in-register per 32-k subchunk.
// B: Wp 32KB chunk staged to LDS via regs, double-buffered (64KB LDS).
// ---------------------------------------------------------------------------
__global__ __launch_bounds__(256) void gemm_ext_kernel(const float* __restrict__ x,
                                                       const ushort_t* __restrict__ Wp,
                                                       const float* __restrict__ bin,
                                                       float* __restrict__ ext) {
    __shared__ __align__(16) ushort_t Bbuf[2][16384];   // 2 x 32KB

    const int tid  = threadIdx.x;
    const int lane = tid & 63;
    const int wave = tid >> 6;
    const int l15  = lane & 15;
    const int lg   = lane >> 4;          // k-group 0..3

    const long rowbase = (long)blockIdx.x * 64 + wave * 16;
    const float* xrow = x + (rowbase + l15) * 1024 + lg * 8;

    f32x4 acc[4];
#pragma unroll
    for (int n = 0; n < 4; ++n) acc[n] = (f32x4){0.f, 0.f, 0.f, 0.f};

    float4 A0[4][2], A1[4][2];
    uint4  Br[8];

    // prologue: A regs for iter 0, B chunk 0 into staging regs
#pragma unroll
    for (int kk = 0; kk < 4; ++kk)
#pragma unroll
        for (int half = 0; half < 2; ++half)
            A0[kk][half] = *(const float4*)(xrow + kk * 32 + half * 4);
#pragma unroll
    for (int r = 0; r < 8; ++r)
        Br[r] = *(const uint4*)(Wp + r * 2048 + tid * 8);

    auto step = [&](int ic, float4 (&Ac)[4][2], float4 (&An)[4][2]) {
        const int buf = ic & 1;
        // commit staged B chunk to LDS (waits on the B loads)
#pragma unroll
        for (int r = 0; r < 8; ++r)
            *(uint4*)(&Bbuf[buf][r * 2048 + tid * 8]) = Br[r];
        __syncthreads();

        // prefetch next chunk (A regs + B staging regs)
        if (ic < 7) {
            const ushort_t* wsrc = Wp + (ic + 1) * 16384;
#pragma unroll
            for (int r = 0; r < 8; ++r)
                Br[r] = *(const uint4*)(wsrc + r * 2048 + tid * 8);
            const float* xs = xrow + (ic + 1) * 128;
#pragma unroll
            for (int kk = 0; kk < 4; ++kk)
#pragma unroll
                for (int half = 0; half < 2; ++half)
                    An[kk][half] = *(const float4*)(xs + kk * 32 + half * 4);
        }

        // compute: 4 sub-chunks of K=32
#pragma unroll
        for (int kk = 0; kk < 4; ++kk) {
            bf16x8 Ahi, Alo;
            split8(Ac[kk][0], Ac[kk][1], Ahi, Alo);
            const ushort_t* bb = &Bbuf[buf][kk * 4096 + lg * 512];
#pragma unroll
            for (int nq = 0; nq < 4; ++nq) {
                bf16x8 bh = *(const bf16x8*)(bb + (nq * 16 + l15) * 8);
                bf16x8 bl = *(const bf16x8*)(bb + 2048 + (nq * 16 + l15) * 8);
                acc[nq] = __builtin_amdgcn_mfma_f32_16x16x32_bf16(Ahi, bh, acc[nq], 0, 0, 0);
                acc[nq] = __builtin_amdgcn_mfma_f32_16x16x32_bf16(Ahi, bl, acc[nq], 0, 0, 0);
                acc[nq] = __builtin_amdgcn_mfma_f32_16x16x32_bf16(Alo, bh, acc[nq], 0, 0, 0);
            }
        }
    };

#pragma unroll 1
    for (int i2 = 0; i2 < 4; ++i2) {
        step(2 * i2,     A0, A1);
        step(2 * i2 + 1, A1, A0);
    }

    // epilogue: add bias, store.  C/D map: col = lane&15, row = (lane>>4)*4 + r
#pragma unroll
    for (int nq = 0; nq < 4; ++nq) {
        float bias = bin[nq * 16 + l15];
        long r0 = rowbase + lg * 4;
#pragma unroll
        for (int r = 0; r < 4; ++r) {
            ext[(r0 + r) * 64 + nq * 16 + l15] = acc[nq][r] + bias;
        }
    }
}

// ---------------------------------------------------------------------------
// Kernel 3: recurrent scan.  One block (1 wave, 64 threads) per batch element.
// (unchanged from R0 for attribution)
// ---------------------------------------------------------------------------
__global__ __launch_bounds__(64) void scan_kernel(const float* __restrict__ ext,
                                                  const float* __restrict__ Wrec,
                                                  const float* __restrict__ brec,
                                                  float* __restrict__ states) {
    const int b = blockIdx.x;
    const int h = threadIdx.x;   // 0..63

    float w[64];
#pragma unroll
    for (int i = 0; i < 16; ++i)
        *(float4*)&w[i * 4] = *(const float4*)&Wrec[h * 64 + i * 4];
    const float bias = brec[h];

    __shared__ float in_lds[2][64];

    const float* ep = ext + (size_t)b * 512 * 64 + h;
    float* sp = states + (size_t)b * 512 * 64 + h;

    float s = 0.f;
    float e0 = ep[0];
    float e1 = ep[64];

    for (int t = 0; t < 512; ++t) {
        float in = s + e0;
        in_lds[t & 1][h] = in;
        e0 = e1;
        if (t + 2 < 512) e1 = ep[(size_t)(t + 2) * 64];
        __syncthreads();

        float a0 = bias, a1 = 0.f, a2 = 0.f, a3 = 0.f;
#pragma unroll
        for (int i = 0; i < 16; ++i) {
            float4 v = *(const float4*)&in_lds[t & 1][i * 4];
            a0 += v.x * w[i * 4 + 0];
            a1 += v.y * w[i * 4 + 1];
            a2 += v.z * w[i * 4 + 2];
            a3 += v.w * w[i * 4 + 3];
        }
        s = fmaxf((a0 + a1) + (a2 + a3), 0.f);
        sp[(size_t)t * 64] = s;
    }
}

// ---------------------------------------------------------------------------
// Kernel 4: output head.  out = relu(states @ W_o1^T + b_o1) @ W_o2^T + b_o2
// (unchanged from R0)
// ---------------------------------------------------------------------------
__global__ __launch_bounds__(256) void head_kernel(const float* __restrict__ states,
                                                   const float* __restrict__ Wo1,
                                                   const float* __restrict__ bo1,
                                                   const float* __restrict__ Wo2,
                                                   const float* __restrict__ bo2,
                                                   float* __restrict__ out) {
    __shared__ float W1t[64][32];   // W1t[k][j] = Wo1[j][k]
    __shared__ float w2s[64];
    __shared__ float b1s[32];
    __shared__ float b2s[2];

    const int tid = threadIdx.x;
    for (int idx = tid; idx < 2048; idx += 256) {
        int j = idx >> 6, k = idx & 63;
        W1t[k][j] = Wo1[idx];
    }
    if (tid < 64) w2s[tid] = Wo2[tid];
    if (tid < 32) b1s[tid] = bo1[tid];
    if (tid < 2)  b2s[tid] = bo2[tid];
    __syncthreads();

    const size_t row = (size_t)blockIdx.x * 256 + tid;  // 0..131071
    const float* srow = states + row * 64;

    float st[64];
#pragma unroll
    for (int i = 0; i < 16; ++i)
        *(float4*)&st[i * 4] = *(const float4*)&srow[i * 4];

    float4 hacc[8];
#pragma unroll
    for (int j4 = 0; j4 < 8; ++j4) hacc[j4] = (float4){0.f, 0.f, 0.f, 0.f};

#pragma unroll
    for (int k = 0; k < 64; ++k) {
        float sk = st[k];
#pragma unroll
        for (int j4 = 0; j4 < 8; ++j4) {
            float4 wv = *(const float4*)&W1t[k][j4 * 4];
            hacc[j4].x += sk * wv.x;
            hacc[j4].y += sk * wv.y;
            hacc[j4].z += sk * wv.z;
            hacc[j4].w += sk * wv.w;
        }
    }

    float o0 = b2s[0], o1 = b2s[1];
#pragma unroll
    for (int j4 = 0; j4 < 8; ++j4) {
        float4 bv = *(const float4*)&b1s[j4 * 4];
        float hj[4] = {fmaxf(hacc[j4].x + bv.x, 0.f), fmaxf(hacc[j4].y + bv.y, 0.f),
                       fmaxf(hacc[j4].z + bv.z, 0.f), fmaxf(hacc[j4].w + bv.w, 0.f)};
#pragma unroll
        for (int r = 0; r < 4; ++r) {
            int j = j4 * 4 + r;
            o0 += hj[r] * w2s[j];
            o1 += hj[r] * w2s[32 + j];
        }
    }
    float2 ov = {o0, o1};
    *(float2*)&out[row * 2] = ov;
}

// ---------------------------------------------------------------------------
extern "C" void kernel_launch(void* const* d_in, const int* in_sizes, int n_in,
                              void* d_out, int out_size, void* d_ws, size_t ws_size,
                              hipStream_t stream) {
    (void)in_sizes; (void)n_in; (void)out_size; (void)ws_size;

    const float* x     = (const float*)d_in[0];
    const float* W_in  = (const float*)d_in[1];
    const float* b_in  = (const float*)d_in[2];
    const float* W_rec = (const float*)d_in[3];
    const float* b_rec = (const float*)d_in[4];
    const float* W_o1  = (const float*)d_in[5];
    const float* b_o1  = (const float*)d_in[6];
    const float* W_o2  = (const float*)d_in[7];
    const float* b_o2  = (const float*)d_in[8];
    float* out = (float*)d_out;

    char* ws = (char*)d_ws;
    ushort_t* Wp   = (ushort_t*)ws;                                  // 256 KB
    float* ext     = (float*)(ws + (1u << 20));                      // 32 MB
    float* states  = (float*)(ws + (1u << 20) + (32u << 20));        // 32 MB

    pack_w_kernel<<<512, 256, 0, stream>>>(W_in, Wp);
    gemm_ext_kernel<<<2048, 256, 0, stream>>>(x, Wp, b_in, ext);
    scan_kernel<<<256, 64, 0, stream>>>(ext, W_rec, b_rec, states);
    head_kernel<<<512, 256, 0, stream>>>(states, W_o1, b_o1, W_o2, b_o2, out);
}

// Round 4
// 394.117 us; speedup vs baseline: 1.3436x; 1.3436x over previous
//
#include <hip/hip_runtime.h>

typedef __attribute__((ext_vector_type(8))) short bf16x8;
typedef __attribute__((ext_vector_type(4))) float f32x4;
typedef unsigned short ushort_t;

// ---------------------------------------------------------------------------
// fp32 -> bf16 RNE helpers
// ---------------------------------------------------------------------------
__device__ inline unsigned f2bf_rnd(float f) {
    unsigned u = __float_as_uint(f);
    return u + 0x7FFFu + ((u >> 16) & 1u);   // high 16 bits = RNE bf16
}

__device__ inline void split8(f32x4 a, f32x4 b, bf16x8& hv, bf16x8& lv) {
    float f[8] = {a.x, a.y, a.z, a.w, b.x, b.y, b.z, b.w};
    unsigned r[8], l[8];
#pragma unroll
    for (int j = 0; j < 8; ++j) r[j] = f2bf_rnd(f[j]);
#pragma unroll
    for (int j = 0; j < 8; ++j) {
        float hf = __uint_as_float(r[j] & 0xFFFF0000u);
        l[j] = f2bf_rnd(f[j] - hf);
    }
    union { unsigned u[4]; bf16x8 v; } H, L;
#pragma unroll
    for (int p = 0; p < 4; ++p) {
        H.u[p] = __builtin_amdgcn_perm(r[2 * p + 1], r[2 * p], 0x07060302u);
        L.u[p] = __builtin_amdgcn_perm(l[2 * p + 1], l[2 * p], 0x07060302u);
    }
    hv = H.v; lv = L.v;
}

// ---------------------------------------------------------------------------
// Kernel 1: pack W_in [64][1024] fp32 -> Wp bf16 hi/lo in MFMA-fragment layout
// Wp layout: [chunk 32][hl 2][kg 4][n 64][j 8]  (ushort), 256 KB total
// ---------------------------------------------------------------------------
__global__ void pack_w_kernel(const float* __restrict__ Win, ushort_t* __restrict__ Wp) {
    int idx = blockIdx.x * 256 + threadIdx.x;   // 0..65535
    int j  = idx & 7;
    int n  = (idx >> 3) & 63;
    int kg = (idx >> 9) & 3;
    int ch = idx >> 11;                          // 0..31
    int k  = ch * 32 + kg * 8 + j;
    float v = Win[n * 1024 + k];
    unsigned hb = f2bf_rnd(v) >> 16;
    float hf = __uint_as_float(hb << 16);
    unsigned lb = f2bf_rnd(v - hf) >> 16;
    Wp[((ch * 2 + 0) * 4 + kg) * 512 + n * 8 + j] = (ushort_t)hb;
    Wp[((ch * 2 + 1) * 4 + kg) * 512 + n * 8 + j] = (ushort_t)lb;
}

// ---------------------------------------------------------------------------
// Kernel 2: ext = x @ W_in^T + b_in  via bf16 MFMA, 3-term hi/lo split.
// M=131072, N=64, K=1024.  Per wave: 32 rows (2 m-quads), BK=32, NO LDS,
// NO barriers.  A: nontemporal global->reg, 2-slot/2-deep pipeline.
// B: 256KB packed Wp read per-fragment from L1/L2 each iter.
// ---------------------------------------------------------------------------
__global__ __launch_bounds__(256) void gemm_ext_kernel(const float* __restrict__ x,
                                                       const ushort_t* __restrict__ Wp,
                                                       const float* __restrict__ bin,
                                                       float* __restrict__ ext) {
    const int tid  = threadIdx.x;
    const int lane = tid & 63;
    const int wave = tid >> 6;
    const int l15  = lane & 15;
    const int lg   = lane >> 4;          // k-group 0..3

    const long rowbase = (long)blockIdx.x * 128 + wave * 32;
    const float* xa0 = x + (rowbase + l15) * 1024 + lg * 8;
    const float* xa1 = xa0 + (long)16 * 1024;

    f32x4 acc[2][4];
#pragma unroll
    for (int m = 0; m < 2; ++m)
#pragma unroll
        for (int n = 0; n < 4; ++n) acc[m][n] = (f32x4){0.f, 0.f, 0.f, 0.f};

    f32x4 As[2][2][2];   // [slot][mq][half]
    // prologue: slot0 <- chunk 0, slot1 <- chunk 1
#pragma unroll
    for (int s = 0; s < 2; ++s) {
        const int ko = s * 32;
        As[s][0][0] = __builtin_nontemporal_load((const f32x4*)(xa0 + ko));
        As[s][0][1] = __builtin_nontemporal_load((const f32x4*)(xa0 + ko + 4));
        As[s][1][0] = __builtin_nontemporal_load((const f32x4*)(xa1 + ko));
        As[s][1][1] = __builtin_nontemporal_load((const f32x4*)(xa1 + ko + 4));
    }

    const ushort_t* bbase = Wp + lg * 512 + l15 * 8;

#pragma unroll 1
    for (int ic = 0; ic < 32; ic += 2) {
#pragma unroll
        for (int sub = 0; sub < 2; ++sub) {
            const int i = ic + sub;
            // convert this chunk's A (waits on loads issued 2 iters ago)
            bf16x8 Ahi[2], Alo[2];
            split8(As[sub][0][0], As[sub][0][1], Ahi[0], Alo[0]);
            split8(As[sub][1][0], As[sub][1][1], Ahi[1], Alo[1]);
            // refill the slot 2 iterations ahead
            if (i + 2 < 32) {
                const int ko = (i + 2) * 32;
                As[sub][0][0] = __builtin_nontemporal_load((const f32x4*)(xa0 + ko));
                As[sub][0][1] = __builtin_nontemporal_load((const f32x4*)(xa0 + ko + 4));
                As[sub][1][0] = __builtin_nontemporal_load((const f32x4*)(xa1 + ko));
                As[sub][1][1] = __builtin_nontemporal_load((const f32x4*)(xa1 + ko + 4));
            }
            // B fragments straight from cache; MFMA
            const ushort_t* bp = bbase + i * 4096;
#pragma unroll
            for (int nq = 0; nq < 4; ++nq) {
                bf16x8 bh = *(const bf16x8*)(bp + nq * 128);
                bf16x8 bl = *(const bf16x8*)(bp + 2048 + nq * 128);
#pragma unroll
                for (int mq = 0; mq < 2; ++mq) {
                    acc[mq][nq] = __builtin_amdgcn_mfma_f32_16x16x32_bf16(Ahi[mq], bh, acc[mq][nq], 0, 0, 0);
                    acc[mq][nq] = __builtin_amdgcn_mfma_f32_16x16x32_bf16(Ahi[mq], bl, acc[mq][nq], 0, 0, 0);
                    acc[mq][nq] = __builtin_amdgcn_mfma_f32_16x16x32_bf16(Alo[mq], bh, acc[mq][nq], 0, 0, 0);
                }
            }
        }
    }

    // epilogue: add bias, store.  C/D map: col = lane&15, row = (lane>>4)*4 + r
#pragma unroll
    for (int nq = 0; nq < 4; ++nq) {
        float bias = bin[nq * 16 + l15];
#pragma unroll
        for (int mq = 0; mq < 2; ++mq) {
            long r0 = rowbase + mq * 16 + lg * 4;
#pragma unroll
            for (int r = 0; r < 4; ++r) {
                ext[(r0 + r) * 64 + nq * 16 + l15] = acc[mq][nq][r] + bias;
            }
        }
    }
}

// ---------------------------------------------------------------------------
// Kernel 3: recurrent scan.  One block (1 wave, 64 threads) per batch element.
// Single wave => no s_barrier needed; LDS visibility via lgkmcnt(0) only, so
// the ext prefetch (vmcnt) stays in flight across iterations.
// ---------------------------------------------------------------------------
__global__ __launch_bounds__(64) void scan_kernel(const float* __restrict__ ext,
                                                  const float* __restrict__ Wrec,
                                                  const float* __restrict__ brec,
                                                  float* __restrict__ states) {
    const int b = blockIdx.x;
    const int h = threadIdx.x;   // 0..63

    float w[64];
#pragma unroll
    for (int i = 0; i < 16; ++i)
        *(float4*)&w[i * 4] = *(const float4*)&Wrec[h * 64 + i * 4];
    const float bias = brec[h];

    __shared__ float in_lds[2][64];

    const float* ep = ext + (size_t)b * 512 * 64 + h;
    float* sp = states + (size_t)b * 512 * 64 + h;

    float s = 0.f;
    float e0 = ep[0];
    float e1 = ep[64];

    for (int t = 0; t < 512; ++t) {
        float in = s + e0;
        in_lds[t & 1][h] = in;
        e0 = e1;
        if (t + 2 < 512) e1 = ep[(size_t)(t + 2) * 64];
        // single-wave block: writes visible after lgkmcnt(0); no barrier, no vmcnt drain
        asm volatile("s_waitcnt lgkmcnt(0)" ::: "memory");

        float a0 = bias, a1 = 0.f, a2 = 0.f, a3 = 0.f;
#pragma unroll
        for (int i = 0; i < 16; ++i) {
            float4 v = *(const float4*)&in_lds[t & 1][i * 4];
            a0 += v.x * w[i * 4 + 0];
            a1 += v.y * w[i * 4 + 1];
            a2 += v.z * w[i * 4 + 2];
            a3 += v.w * w[i * 4 + 3];
        }
        s = fmaxf((a0 + a1) + (a2 + a3), 0.f);
        sp[(size_t)t * 64] = s;
    }
}

// ---------------------------------------------------------------------------
// Kernel 4: output head.  out = relu(states @ W_o1^T + b_o1) @ W_o2^T + b_o2
// ---------------------------------------------------------------------------
__global__ __launch_bounds__(256) void head_kernel(const float* __restrict__ states,
                                                   const float* __restrict__ Wo1,
                                                   const float* __restrict__ bo1,
                                                   const float* __restrict__ Wo2,
                                                   const float* __restrict__ bo2,
                                                   float* __restrict__ out) {
    __shared__ float W1t[64][32];   // W1t[k][j] = Wo1[j][k]
    __shared__ float w2s[64];
    __shared__ float b1s[32];
    __shared__ float b2s[2];

    const int tid = threadIdx.x;
    for (int idx = tid; idx < 2048; idx += 256) {
        int j = idx >> 6, k = idx & 63;
        W1t[k][j] = Wo1[idx];
    }
    if (tid < 64) w2s[tid] = Wo2[tid];
    if (tid < 32) b1s[tid] = bo1[tid];
    if (tid < 2)  b2s[tid] = bo2[tid];
    __syncthreads();

    const size_t row = (size_t)blockIdx.x * 256 + tid;  // 0..131071
    const float* srow = states + row * 64;

    float st[64];
#pragma unroll
    for (int i = 0; i < 16; ++i)
        *(float4*)&st[i * 4] = *(const float4*)&srow[i * 4];

    float4 hacc[8];
#pragma unroll
    for (int j4 = 0; j4 < 8; ++j4) hacc[j4] = (float4){0.f, 0.f, 0.f, 0.f};

#pragma unroll
    for (int k = 0; k < 64; ++k) {
        float sk = st[k];
#pragma unroll
        for (int j4 = 0; j4 < 8; ++j4) {
            float4 wv = *(const float4*)&W1t[k][j4 * 4];
            hacc[j4].x += sk * wv.x;
            hacc[j4].y += sk * wv.y;
            hacc[j4].z += sk * wv.z;
            hacc[j4].w += sk * wv.w;
        }
    }

    float o0 = b2s[0], o1 = b2s[1];
#pragma unroll
    for (int j4 = 0; j4 < 8; ++j4) {
        float4 bv = *(const float4*)&b1s[j4 * 4];
        float hj[4] = {fmaxf(hacc[j4].x + bv.x, 0.f), fmaxf(hacc[j4].y + bv.y, 0.f),
                       fmaxf(hacc[j4].z + bv.z, 0.f), fmaxf(hacc[j4].w + bv.w, 0.f)};
#pragma unroll
        for (int r = 0; r < 4; ++r) {
            int j = j4 * 4 + r;
            o0 += hj[r] * w2s[j];
            o1 += hj[r] * w2s[32 + j];
        }
    }
    float2 ov = {o0, o1};
    *(float2*)&out[row * 2] = ov;
}

// ---------------------------------------------------------------------------
extern "C" void kernel_launch(void* const* d_in, const int* in_sizes, int n_in,
                              void* d_out, int out_size, void* d_ws, size_t ws_size,
                              hipStream_t stream) {
    (void)in_sizes; (void)n_in; (void)out_size; (void)ws_size;

    const float* x     = (const float*)d_in[0];
    const float* W_in  = (const float*)d_in[1];
    const float* b_in  = (const float*)d_in[2];
    const float* W_rec = (const float*)d_in[3];
    const float* b_rec = (const float*)d_in[4];
    const float* W_o1  = (const float*)d_in[5];
    const float* b_o1  = (const float*)d_in[6];
    const float* W_o2  = (const float*)d_in[7];
    const float* b_o2  = (const float*)d_in[8];
    float* out = (float*)d_out;

    char* ws = (char*)d_ws;
    ushort_t* Wp   = (ushort_t*)ws;                                  // 256 KB
    float* ext     = (float*)(ws + (1u << 20));                      // 32 MB
    float* states  = (float*)(ws + (1u << 20) + (32u << 20));        // 32 MB

    pack_w_kernel<<<256, 256, 0, stream>>>(W_in, Wp);
    gemm_ext_kernel<<<1024, 256, 0, stream>>>(x, Wp, b_in, ext);
    scan_kernel<<<256, 64, 0, stream>>>(ext, W_rec, b_rec, states);
    head_kernel<<<512, 256, 0, stream>>>(states, W_o1, b_o1, W_o2, b_o2, out);
}